// Round 4
// baseline (173.555 us; speedup 1.0000x reference)
//
#include <hip/hip_runtime.h>

// Embedding gather: out[i, :] = table[idx[i], :]
// N_IDX = 1,048,576 rows, D = 128 fp32 (512 B per row).
//
// 32 lanes per row, one 16B vector per lane -> each half-wave moves one
// contiguous 512 B row. NT stores keep the zero-reuse output stream out of
// L2/L3 (R3: -11%). This round: persistent grid-stride blocks (2048 blocks
// = 8192 waves = device wave capacity) with 4 rows in flight per thread,
// replacing 524K one-shot waves -> amortize wave prologue, raise MLP.

typedef float f32x4 __attribute__((ext_vector_type(4)));

constexpr int BLOCK = 256;
constexpr int ROWS_PER_ITER = BLOCK / 32;  // 8 rows per block per sub-iter
constexpr int UNROLL = 4;                  // 4 gathers in flight per thread

__global__ __launch_bounds__(BLOCK) void embed_gather_kernel(
    const int* __restrict__ idx,
    const f32x4* __restrict__ table,    // [N_EMB * 32] 16B vectors
    f32x4* __restrict__ out,            // [N_IDX * 32]
    int n_idx) {
  const int col = threadIdx.x & 31;     // 16B chunk within row
  const int sub = threadIdx.x >> 5;     // row slot within block (0..7)
  const long step = (long)gridDim.x * ROWS_PER_ITER * UNROLL;

  for (long base = (long)blockIdx.x * ROWS_PER_ITER * UNROLL + sub;
       base < n_idx; base += step) {
    f32x4 v[UNROLL];
    long  r[UNROLL];
#pragma unroll
    for (int u = 0; u < UNROLL; ++u) {
      r[u] = base + (long)u * ROWS_PER_ITER;
      if (r[u] < n_idx) {
        int src = idx[r[u]];                       // broadcast within 32 lanes
        v[u] = table[(size_t)src * 32 + col];      // cached read (has reuse)
      }
    }
#pragma unroll
    for (int u = 0; u < UNROLL; ++u) {
      if (r[u] < n_idx)
        __builtin_nontemporal_store(v[u], &out[(size_t)r[u] * 32 + col]);
    }
  }
}

extern "C" void kernel_launch(void* const* d_in, const int* in_sizes, int n_in,
                              void* d_out, int out_size, void* d_ws, size_t ws_size,
                              hipStream_t stream) {
  const int*   idx   = (const int*)d_in[0];       // "input": int indices [N_IDX]
  const f32x4* table = (const f32x4*)d_in[1];     // "table": fp32 [N_EMB, 128]
  f32x4*       out   = (f32x4*)d_out;             // fp32 [N_IDX, 128]

  int n_idx = in_sizes[0];
  // 2048 blocks x 4 waves = 8192 waves = 256 CU x 32 waves/CU.
  int grid = 2048;

  embed_gather_kernel<<<grid, BLOCK, 0, stream>>>(idx, table, out, n_idx);
}

// Round 5
// 171.833 us; speedup vs baseline: 1.0100x; 1.0100x over previous
//
#include <hip/hip_runtime.h>

// Embedding gather: out[i, :] = table[idx[i], :]
// N_IDX = 1,048,576 rows, D = 128 fp32 (512 B per row).
//
// Final form (R3 revert): 32 lanes per row, one 16B vector per lane -> each
// half-wave moves one contiguous 512 B row. NT stores keep the zero-reuse
// output stream out of L2/L3 so the table's ~333 MB unique footprint (1.6x
// reuse) stays cached (R3: -11%). R4 showed persistent blocks + deeper MLP
// are neutral -> the kernel is HBM-bound at ~5.6 TB/s effective (85% of the
// 6.6 TB/s pure-stream ceiling); the residual gap is the random-512B-segment
// DRAM locality penalty, structural to the given index order.

typedef float f32x4 __attribute__((ext_vector_type(4)));

__global__ __launch_bounds__(256) void embed_gather_kernel(
    const int* __restrict__ idx,
    const f32x4* __restrict__ table,    // [N_EMB * 32] 16B vectors
    f32x4* __restrict__ out,            // [N_IDX * 32]
    int n_idx) {
  int t = blockIdx.x * 256 + threadIdx.x;
  int row = t >> 5;        // which output row
  int col = t & 31;        // which 16B chunk within the row (32 * 16B = 512B)
  if (row < n_idx) {
    int src = idx[row];    // lanes 0-31 / 32-63 broadcast two addresses per wave
    f32x4 v = table[(size_t)src * 32 + col];                       // cached read
    __builtin_nontemporal_store(v, &out[(size_t)row * 32 + col]);  // nt write
  }
}

extern "C" void kernel_launch(void* const* d_in, const int* in_sizes, int n_in,
                              void* d_out, int out_size, void* d_ws, size_t ws_size,
                              hipStream_t stream) {
  const int*   idx   = (const int*)d_in[0];       // "input": int indices [N_IDX]
  const f32x4* table = (const f32x4*)d_in[1];     // "table": fp32 [N_EMB, 128]
  f32x4*       out   = (f32x4*)d_out;             // fp32 [N_IDX, 128]

  int n_idx = in_sizes[0];
  int total_threads = n_idx * 32;                 // 32 threads per row
  int block = 256;
  int grid = (total_threads + block - 1) / block;

  embed_gather_kernel<<<grid, block, 0, stream>>>(idx, table, out, n_idx);
}